// Round 1
// baseline (2511.846 us; speedup 1.0000x reference)
//
#include <hip/hip_runtime.h>

#define NN     10000
#define DI     128
#define DO     256
#define KNB    32
#define NSRC   33      // 32 neighbors + self
#define CHUNK  1024
#define NCHUNK 10      // ceil(10000/1024)
#define RB     16      // rows per block in distance/gemm kernels
#define NPAD   10016
#define NEG    0.2f

// monotone map f32 -> u32 preserving < order (handles negatives)
__device__ __forceinline__ unsigned fkey(float f) {
    unsigned u = __float_as_uint(f);
    return (u & 0x80000000u) ? ~u : (u | 0x80000000u);
}

__global__ void cast_k(const float* __restrict__ x, double* __restrict__ x64) {
    int idx = blockIdx.x * 256 + threadIdx.x;
    if (idx < NN * DI) x64[idx] = (double)x[idx];
}

__global__ void transpose64_k(const float* __restrict__ x, double* __restrict__ xT64) {
    int j = blockIdx.x * 256 + threadIdx.x;
    int d = blockIdx.y;
    if (j < NPAD) xT64[(size_t)d * NPAD + j] = (j < NN) ? (double)x[(size_t)j * DI + d] : 0.0;
}

__global__ void sq64_k(const double* __restrict__ xT64, double* __restrict__ sq64) {
    int j = blockIdx.x * 256 + threadIdx.x;
    if (j >= NPAD) return;
    double s = 0.0;
    for (int d = 0; d < DI; ++d) {
        double v = xT64[(size_t)d * NPAD + j];
        s = fma(v, v, s);
    }
    sq64[j] = s;
}

// h_l = x@W_l + b_l ; h_r = x@W_r + b_r  (f32 vector FMA, 16 rows/block, col=thread)
__global__ __launch_bounds__(256) void hgemm_k(
    const float* __restrict__ x, const float* __restrict__ Wl,
    const float* __restrict__ bl, const float* __restrict__ Wr,
    const float* __restrict__ br, float* __restrict__ hl, float* __restrict__ hr)
{
    const int c = threadIdx.x;
    const int r0 = blockIdx.x * RB;
    float accl[RB], accr[RB];
    const float blv = bl[c], brv = br[c];
#pragma unroll
    for (int r = 0; r < RB; ++r) { accl[r] = blv; accr[r] = brv; }
    for (int d = 0; d < DI; ++d) {
        const float wl = Wl[d * DO + c];
        const float wr = Wr[d * DO + c];
#pragma unroll
        for (int r = 0; r < RB; ++r) {
            const float xv = x[(size_t)(r0 + r) * DI + d];  // wave-uniform -> s_load
            accl[r] = fmaf(xv, wl, accl[r]);
            accr[r] = fmaf(xv, wr, accr[r]);
        }
    }
#pragma unroll
    for (int r = 0; r < RB; ++r) {
        hl[(size_t)(r0 + r) * DO + c] = accl[r];
        hr[(size_t)(r0 + r) * DO + c] = accr[r];
    }
}

// distances (f64, rounded to f32) for a 16-row x 1024-col tile + per-row top-32
__global__ __launch_bounds__(256) void knn_partial_k(
    const double* __restrict__ x64, const double* __restrict__ xT64,
    const double* __restrict__ sq64, unsigned long long* __restrict__ keys)
{
    __shared__ float dist[RB][CHUNK];   // 64 KB
    const int r0 = blockIdx.x * RB;
    const int cbase = blockIdx.y * CHUNK;
    const int t = threadIdx.x;
    const float FINF = __int_as_float(0x7f800000);

    for (int s = 0; s < CHUNK / 256; ++s) {
        const int pos = t + 256 * s;
        const int j = cbase + pos;
        if (j < NN) {
            double acc[RB];
#pragma unroll
            for (int r = 0; r < RB; ++r) acc[r] = 0.0;
            for (int d = 0; d < DI; ++d) {
                const double xv = xT64[(size_t)d * NPAD + j];   // coalesced
#pragma unroll
                for (int r = 0; r < RB; ++r)
                    acc[r] = fma(x64[(size_t)(r0 + r) * DI + d], xv, acc[r]); // uniform
            }
            const double sqj = sq64[j];
#pragma unroll
            for (int r = 0; r < RB; ++r) {
                float dd = (float)(sq64[r0 + r] + sqj - 2.0 * acc[r]);
                if (j == r0 + r) dd = FINF;   // diagonal masked (loop=False)
                dist[r][pos] = dd;
            }
        } else {
#pragma unroll
            for (int r = 0; r < RB; ++r) dist[r][pos] = FINF;
        }
    }
    __syncthreads();

    // wave w selects rows w*4..w*4+3, barrier-free iterative argmin in registers
    const int wid = t >> 6, lane = t & 63;
    for (int rr = 0; rr < RB / 4; ++rr) {
        const int r = wid * (RB / 4) + rr;
        unsigned long long key[CHUNK / 64];
#pragma unroll
        for (int u = 0; u < CHUNK / 64; ++u) {
            const int pos = lane + 64 * u;                     // bank-conflict-free
            key[u] = ((unsigned long long)fkey(dist[r][pos]) << 32)
                   | (unsigned)(cbase + pos);
        }
        unsigned long long* outp = keys + ((size_t)(r0 + r) * NCHUNK + blockIdx.y) * KNB;
        for (int k = 0; k < KNB; ++k) {
            unsigned long long m = key[0];
#pragma unroll
            for (int u = 1; u < CHUNK / 64; ++u) m = key[u] < m ? key[u] : m;
#pragma unroll
            for (int off = 32; off >= 1; off >>= 1) {
                unsigned long long o = __shfl_xor(m, off);
                m = o < m ? o : m;
            }
#pragma unroll
            for (int u = 0; u < CHUNK / 64; ++u)
                if (key[u] == m) { key[u] = ~0ull; outp[k] = m; }  // unique winner
        }
    }
}

// merge 10 chunk-lists of 32 -> final 32 per row (one wave per row)
__global__ void knn_merge_k(const unsigned long long* __restrict__ keys,
                            int* __restrict__ nbr)
{
    const int i = blockIdx.x;
    const int lane = threadIdx.x;   // 64 threads
    unsigned long long key[(NCHUNK * KNB) / 64];   // 5
#pragma unroll
    for (int u = 0; u < (NCHUNK * KNB) / 64; ++u)
        key[u] = keys[(size_t)i * (NCHUNK * KNB) + lane + 64 * u];
    for (int k = 0; k < KNB; ++k) {
        unsigned long long m = key[0];
#pragma unroll
        for (int u = 1; u < (NCHUNK * KNB) / 64; ++u) m = key[u] < m ? key[u] : m;
#pragma unroll
        for (int off = 32; off >= 1; off >>= 1) {
            unsigned long long o = __shfl_xor(m, off);
            m = o < m ? o : m;
        }
#pragma unroll
        for (int u = 0; u < (NCHUNK * KNB) / 64; ++u)
            if (key[u] == m) { key[u] = ~0ull; nbr[(size_t)i * KNB + k] = (int)(m & 0xffffffffu); }
    }
}

// attention epilogue: block=row, thread=output dim (DO==256==blockDim)
__global__ __launch_bounds__(256) void gat_k(
    const float* __restrict__ hl, const float* __restrict__ hr,
    const int* __restrict__ nbr, const float* __restrict__ att,
    const float* __restrict__ bias, float* __restrict__ out)
{
    __shared__ int src[NSRC];
    __shared__ float eP[NSRC][4];
    __shared__ float eS[NSRC];
    const int i = blockIdx.x, t = threadIdx.x;
    if (t < KNB) src[t] = nbr[(size_t)i * KNB + t];
    if (t == KNB) src[KNB] = i;   // self-loop appended last, like the reference
    __syncthreads();
    const float at  = att[t];
    const float hrv = hr[(size_t)i * DO + t];
    float hlv[NSRC];
#pragma unroll
    for (int k = 0; k < NSRC; ++k) {
        const float v = hl[(size_t)src[k] * DO + t];
        hlv[k] = v;
        const float z = v + hrv;
        float p = (z > 0.f ? z : NEG * z) * at;
#pragma unroll
        for (int off = 32; off >= 1; off >>= 1) p += __shfl_xor(p, off);
        if ((t & 63) == 0) eP[k][t >> 6] = p;
    }
    __syncthreads();
    if (t < NSRC) eS[t] = eP[t][0] + eP[t][1] + eP[t][2] + eP[t][3];
    __syncthreads();
    float m = eS[0];
#pragma unroll
    for (int k = 1; k < NSRC; ++k) m = fmaxf(m, eS[k]);
    float w[NSRC];
    float ssum = 0.f;
#pragma unroll
    for (int k = 0; k < NSRC; ++k) { w[k] = expf(eS[k] - m); ssum += w[k]; }
    const float inv = 1.f / ssum;
    float o = bias[t];
#pragma unroll
    for (int k = 0; k < NSRC; ++k) o = fmaf(w[k] * inv, hlv[k], o);
    out[(size_t)i * DO + t] = o;
}

extern "C" void kernel_launch(void* const* d_in, const int* in_sizes, int n_in,
                              void* d_out, int out_size, void* d_ws, size_t ws_size,
                              hipStream_t stream) {
    const float* x    = (const float*)d_in[0];
    const float* Wl   = (const float*)d_in[1];
    const float* bl   = (const float*)d_in[2];
    const float* Wr   = (const float*)d_in[3];
    const float* br   = (const float*)d_in[4];
    const float* att  = (const float*)d_in[5];
    const float* bias = (const float*)d_in[6];
    float* out = (float*)d_out;

    char* ws = (char*)d_ws;
    // layout (bytes):
    double* x64  = (double*)(ws + 0);          // 10,240,000
    double* xT64 = (double*)(ws + 10240000);   // 10,256,384
    double* sq64 = (double*)(ws + 20496384);   //     80,128
    float*  hl   = (float*)(ws + 20576512);    // 10,240,000
    float*  hr   = (float*)(ws + 30816512);    // 10,240,000
    int*    nbr  = (int*)(ws + 41056512);      //  1,280,000
    unsigned long long* keys = (unsigned long long*)(ws + 42336512); // 25,600,000
    // total ~68 MB

    cast_k<<<dim3((NN * DI + 255) / 256), 256, 0, stream>>>(x, x64);
    transpose64_k<<<dim3((NPAD + 255) / 256, DI), 256, 0, stream>>>(x, xT64);
    sq64_k<<<dim3((NPAD + 255) / 256), 256, 0, stream>>>(xT64, sq64);
    hgemm_k<<<dim3(NN / RB), 256, 0, stream>>>(x, Wl, bl, Wr, br, hl, hr);
    knn_partial_k<<<dim3(NN / RB, NCHUNK), 256, 0, stream>>>(x64, xT64, sq64, keys);
    knn_merge_k<<<dim3(NN), 64, 0, stream>>>(keys, nbr);
    gat_k<<<dim3(NN), 256, 0, stream>>>(hl, hr, nbr, att, bias, out);
}

// Round 2
// 2229.559 us; speedup vs baseline: 1.1266x; 1.1266x over previous
//
#include <hip/hip_runtime.h>

#define NN     10000
#define DI     128
#define DO     256
#define KNB    32
#define NSRC   33      // 32 neighbors + self
#define CHUNK  1024
#define NCHUNK 10      // NP2 / CHUNK
#define RB     16      // rows per block in distance/gemm kernels
#define NP2    10240   // padded column count (multiple of CHUNK)
#define CAND   64      // f32 candidates kept per row for f64 re-rank
#define NEG    0.2f

// monotone map f32 -> u32 preserving < order (handles negatives)
__device__ __forceinline__ unsigned fkey(float f) {
    unsigned u = __float_as_uint(f);
    return (u & 0x80000000u) ? ~u : (u | 0x80000000u);
}

__global__ void cast_k(const float* __restrict__ x, double* __restrict__ x64) {
    int idx = blockIdx.x * 256 + threadIdx.x;
    if (idx < NN * DI) x64[idx] = (double)x[idx];
}

__global__ void transpose32_k(const float* __restrict__ x, float* __restrict__ xT) {
    int j = blockIdx.x * 256 + threadIdx.x;
    int d = blockIdx.y;
    if (j < NP2) xT[(size_t)d * NP2 + j] = (j < NN) ? x[(size_t)j * DI + d] : 0.f;
}

// per-row squared norms: exact-ish f64, plus padded f32 copy for pass A
__global__ void sqrow_k(const double* __restrict__ x64, double* __restrict__ sq64,
                        float* __restrict__ sq32) {
    int i = blockIdx.x * 256 + threadIdx.x;
    if (i >= NP2) return;
    if (i < NN) {
        double s = 0.0;
        for (int d = 0; d < DI; ++d) {
            double v = x64[(size_t)i * DI + d];
            s = fma(v, v, s);
        }
        sq64[i] = s;
        sq32[i] = (float)s;
    } else {
        sq32[i] = 0.f;
    }
}

// h_l = x@W_l + b_l ; h_r = x@W_r + b_r  (f32 vector FMA, 16 rows/block, col=thread)
__global__ __launch_bounds__(256) void hgemm_k(
    const float* __restrict__ x, const float* __restrict__ Wl,
    const float* __restrict__ bl, const float* __restrict__ Wr,
    const float* __restrict__ br, float* __restrict__ hl, float* __restrict__ hr)
{
    const int c = threadIdx.x;
    const int r0 = blockIdx.x * RB;
    float accl[RB], accr[RB];
    const float blv = bl[c], brv = br[c];
#pragma unroll
    for (int r = 0; r < RB; ++r) { accl[r] = blv; accr[r] = brv; }
    for (int d = 0; d < DI; ++d) {
        const float wl = Wl[d * DO + c];
        const float wr = Wr[d * DO + c];
#pragma unroll
        for (int r = 0; r < RB; ++r) {
            const float xv = x[(size_t)(r0 + r) * DI + d];  // wave-uniform -> s_load
            accl[r] = fmaf(xv, wl, accl[r]);
            accr[r] = fmaf(xv, wr, accr[r]);
        }
    }
#pragma unroll
    for (int r = 0; r < RB; ++r) {
        hl[(size_t)(r0 + r) * DO + c] = accl[r];
        hr[(size_t)(r0 + r) * DO + c] = accr[r];
    }
}

// f32 distances for a 16-row x 1024-col tile + per-row per-chunk top-32.
// Each thread owns 4 columns, interleaved in the d-loop (4 loads in flight,
// 64 f32 FMAs per iteration).
__global__ __launch_bounds__(256) void knn_partial_k(
    const float* __restrict__ x, const float* __restrict__ xT,
    const float* __restrict__ sq32, unsigned long long* __restrict__ keys)
{
    __shared__ float dist[RB][CHUNK];   // 64 KB
    const int r0 = blockIdx.x * RB;
    const int cbase = blockIdx.y * CHUNK;
    const int t = threadIdx.x;
    const float FINF = __int_as_float(0x7f800000);

    float acc[RB][4];
#pragma unroll
    for (int r = 0; r < RB; ++r)
#pragma unroll
        for (int s = 0; s < 4; ++s) acc[r][s] = 0.f;

    for (int d = 0; d < DI; ++d) {
        float xv[4];
#pragma unroll
        for (int s = 0; s < 4; ++s)
            xv[s] = xT[(size_t)d * NP2 + cbase + t + 256 * s];   // coalesced
#pragma unroll
        for (int r = 0; r < RB; ++r) {
            const float xr = x[(size_t)(r0 + r) * DI + d];       // uniform -> s_load
#pragma unroll
            for (int s = 0; s < 4; ++s)
                acc[r][s] = fmaf(xr, xv[s], acc[r][s]);
        }
    }

#pragma unroll
    for (int s = 0; s < 4; ++s) {
        const int pos = t + 256 * s;
        const int j = cbase + pos;
        const float sqj = sq32[j];
#pragma unroll
        for (int r = 0; r < RB; ++r) {
            float dd = sq32[r0 + r] + sqj - 2.f * acc[r][s];
            if (j >= NN || j == r0 + r) dd = FINF;   // pad + diagonal mask
            dist[r][pos] = dd;
        }
    }
    __syncthreads();

    // wave w selects rows w*4..w*4+3, barrier-free iterative argmin in registers
    const int wid = t >> 6, lane = t & 63;
    for (int rr = 0; rr < RB / 4; ++rr) {
        const int r = wid * (RB / 4) + rr;
        unsigned long long key[CHUNK / 64];
#pragma unroll
        for (int u = 0; u < CHUNK / 64; ++u) {
            const int pos = lane + 64 * u;                       // bank-conflict-free
            key[u] = ((unsigned long long)fkey(dist[r][pos]) << 32)
                   | (unsigned)(cbase + pos);
        }
        unsigned long long* outp = keys + ((size_t)(r0 + r) * NCHUNK + blockIdx.y) * KNB;
        for (int k = 0; k < KNB; ++k) {
            unsigned long long m = key[0];
#pragma unroll
            for (int u = 1; u < CHUNK / 64; ++u) m = key[u] < m ? key[u] : m;
#pragma unroll
            for (int off = 32; off >= 1; off >>= 1) {
                unsigned long long o = __shfl_xor(m, off);
                m = o < m ? o : m;
            }
#pragma unroll
            for (int u = 0; u < CHUNK / 64; ++u)
                if (key[u] == m) { key[u] = ~0ull; outp[k] = m; }  // unique winner
        }
    }
}

// merge 10 chunk-lists of 32 -> top-64 f32 candidates per row (one wave per row)
__global__ void knn_merge_k(const unsigned long long* __restrict__ keys,
                            int* __restrict__ cand)
{
    const int i = blockIdx.x;
    const int lane = threadIdx.x;   // 64 threads
    unsigned long long key[(NCHUNK * KNB) / 64];   // 5
#pragma unroll
    for (int u = 0; u < (NCHUNK * KNB) / 64; ++u)
        key[u] = keys[(size_t)i * (NCHUNK * KNB) + lane + 64 * u];
    for (int k = 0; k < CAND; ++k) {
        unsigned long long m = key[0];
#pragma unroll
        for (int u = 1; u < (NCHUNK * KNB) / 64; ++u) m = key[u] < m ? key[u] : m;
#pragma unroll
        for (int off = 32; off >= 1; off >>= 1) {
            unsigned long long o = __shfl_xor(m, off);
            m = o < m ? o : m;
        }
#pragma unroll
        for (int u = 0; u < (NCHUNK * KNB) / 64; ++u)
            if (key[u] == m) key[u] = ~0ull;   // remove winner
        if (lane == 0) cand[(size_t)i * CAND + k] = (int)(m & 0xffffffffu);
    }
}

// exact f64 re-rank of the 64 candidates -> final top-32 (lane = candidate)
__global__ void rerank_k(const double* __restrict__ x64, const double* __restrict__ sq64,
                         const int* __restrict__ cand, int* __restrict__ nbr)
{
    const int i = blockIdx.x;
    const int lane = threadIdx.x;   // 64
    const int c = cand[(size_t)i * CAND + lane];
    double acc = 0.0;
    for (int d = 0; d < DI; ++d)
        acc = fma(x64[(size_t)i * DI + d], x64[(size_t)c * DI + d], acc);
    const float dd = (float)(sq64[i] + sq64[c] - 2.0 * acc);
    unsigned long long key = ((unsigned long long)fkey(dd) << 32) | (unsigned)c;
    for (int k = 0; k < KNB; ++k) {
        unsigned long long m = key;
#pragma unroll
        for (int off = 32; off >= 1; off >>= 1) {
            unsigned long long o = __shfl_xor(m, off);
            m = o < m ? o : m;
        }
        if (key == m) key = ~0ull;   // unique winner removed
        if (lane == 0) nbr[(size_t)i * KNB + k] = (int)(m & 0xffffffffu);
    }
}

// attention epilogue: block=row, thread=output dim (DO==256==blockDim)
__global__ __launch_bounds__(256) void gat_k(
    const float* __restrict__ hl, const float* __restrict__ hr,
    const int* __restrict__ nbr, const float* __restrict__ att,
    const float* __restrict__ bias, float* __restrict__ out)
{
    __shared__ int src[NSRC];
    __shared__ float eP[NSRC][4];
    __shared__ float eS[NSRC];
    const int i = blockIdx.x, t = threadIdx.x;
    if (t < KNB) src[t] = nbr[(size_t)i * KNB + t];
    if (t == KNB) src[KNB] = i;   // self-loop appended last, like the reference
    __syncthreads();
    const float at  = att[t];
    const float hrv = hr[(size_t)i * DO + t];
    float hlv[NSRC];
#pragma unroll
    for (int k = 0; k < NSRC; ++k) {
        const float v = hl[(size_t)src[k] * DO + t];
        hlv[k] = v;
        const float z = v + hrv;
        float p = (z > 0.f ? z : NEG * z) * at;
#pragma unroll
        for (int off = 32; off >= 1; off >>= 1) p += __shfl_xor(p, off);
        if ((t & 63) == 0) eP[k][t >> 6] = p;
    }
    __syncthreads();
    if (t < NSRC) eS[t] = eP[t][0] + eP[t][1] + eP[t][2] + eP[t][3];
    __syncthreads();
    float m = eS[0];
#pragma unroll
    for (int k = 1; k < NSRC; ++k) m = fmaxf(m, eS[k]);
    float w[NSRC];
    float ssum = 0.f;
#pragma unroll
    for (int k = 0; k < NSRC; ++k) { w[k] = expf(eS[k] - m); ssum += w[k]; }
    const float inv = 1.f / ssum;
    float o = bias[t];
#pragma unroll
    for (int k = 0; k < NSRC; ++k) o = fmaf(w[k] * inv, hlv[k], o);
    out[(size_t)i * DO + t] = o;
}

extern "C" void kernel_launch(void* const* d_in, const int* in_sizes, int n_in,
                              void* d_out, int out_size, void* d_ws, size_t ws_size,
                              hipStream_t stream) {
    const float* x    = (const float*)d_in[0];
    const float* Wl   = (const float*)d_in[1];
    const float* bl   = (const float*)d_in[2];
    const float* Wr   = (const float*)d_in[3];
    const float* br   = (const float*)d_in[4];
    const float* att  = (const float*)d_in[5];
    const float* bias = (const float*)d_in[6];
    float* out = (float*)d_out;

    char* ws = (char*)d_ws;
    // layout (bytes):
    double* x64  = (double*)(ws + 0);           // 10,240,000
    float*  xT   = (float*)(ws + 10240000);     //  5,242,880
    double* sq64 = (double*)(ws + 15482880);    //     80,000
    float*  sq32 = (float*)(ws + 15562880);     //     40,960
    float*  hl   = (float*)(ws + 15603840);     // 10,240,000
    float*  hr   = (float*)(ws + 25843840);     // 10,240,000
    unsigned long long* keys = (unsigned long long*)(ws + 36083840); // 25,600,000
    int*    cand = (int*)(ws + 61683840);       //  2,560,000
    int*    nbr  = (int*)(ws + 64243840);       //  1,280,000
    // total ~65.5 MB

    cast_k<<<dim3((NN * DI + 255) / 256), 256, 0, stream>>>(x, x64);
    transpose32_k<<<dim3(NP2 / 256, DI), 256, 0, stream>>>(x, xT);
    sqrow_k<<<dim3(NP2 / 256), 256, 0, stream>>>(x64, sq64, sq32);
    hgemm_k<<<dim3(NN / RB), 256, 0, stream>>>(x, Wl, bl, Wr, br, hl, hr);
    knn_partial_k<<<dim3(NN / RB, NCHUNK), 256, 0, stream>>>(x, xT, sq32, keys);
    knn_merge_k<<<dim3(NN), 64, 0, stream>>>(keys, cand);
    rerank_k<<<dim3(NN), 64, 0, stream>>>(x64, sq64, cand, nbr);
    gat_k<<<dim3(NN), 256, 0, stream>>>(hl, hr, nbr, att, bias, out);
}

// Round 3
// 926.290 us; speedup vs baseline: 2.7117x; 2.4070x over previous
//
#include <hip/hip_runtime.h>

#define NN     10000
#define DI     128
#define DO     256
#define KNB    32
#define NSRC   33      // 32 neighbors + self
#define CHUNK  1024
#define NCHUNK 10      // NP2 / CHUNK
#define RB     16      // rows per block in distance/gemm kernels
#define NP2    10240   // padded column count (multiple of CHUNK)
#define CAND   64      // f32 candidates kept per row for f64 re-rank
#define NEG    0.2f

// monotone map f32 -> u32 preserving < order (handles negatives)
__device__ __forceinline__ unsigned fkey(float f) {
    unsigned u = __float_as_uint(f);
    return (u & 0x80000000u) ? ~u : (u | 0x80000000u);
}

__global__ void cast_k(const float* __restrict__ x, double* __restrict__ x64) {
    int idx = blockIdx.x * 256 + threadIdx.x;
    if (idx < NN * DI) x64[idx] = (double)x[idx];
}

__global__ void transpose32_k(const float* __restrict__ x, float* __restrict__ xT) {
    int j = blockIdx.x * 256 + threadIdx.x;
    int d = blockIdx.y;
    if (j < NP2) xT[(size_t)d * NP2 + j] = (j < NN) ? x[(size_t)j * DI + d] : 0.f;
}

// per-row squared norms: exact f64, plus padded f32 copy for the f32 pass
__global__ void sqrow_k(const double* __restrict__ x64, double* __restrict__ sq64,
                        float* __restrict__ sq32) {
    int i = blockIdx.x * 256 + threadIdx.x;
    if (i >= NP2) return;
    if (i < NN) {
        double s = 0.0;
        for (int d = 0; d < DI; ++d) {
            double v = x64[(size_t)i * DI + d];
            s = fma(v, v, s);
        }
        sq64[i] = s;
        sq32[i] = (float)s;
    } else {
        sq32[i] = 0.f;
    }
}

// h_l = x@W_l + b_l ; h_r = x@W_r + b_r  (f32 vector FMA, 16 rows/block, col=thread)
__global__ __launch_bounds__(256) void hgemm_k(
    const float* __restrict__ x, const float* __restrict__ Wl,
    const float* __restrict__ bl, const float* __restrict__ Wr,
    const float* __restrict__ br, float* __restrict__ hl, float* __restrict__ hr)
{
    const int c = threadIdx.x;
    const int r0 = blockIdx.x * RB;
    float accl[RB], accr[RB];
    const float blv = bl[c], brv = br[c];
#pragma unroll
    for (int r = 0; r < RB; ++r) { accl[r] = blv; accr[r] = brv; }
    for (int d = 0; d < DI; ++d) {
        const float wl = Wl[d * DO + c];
        const float wr = Wr[d * DO + c];
#pragma unroll
        for (int r = 0; r < RB; ++r) {
            const float xv = x[(size_t)(r0 + r) * DI + d];  // wave-uniform
            accl[r] = fmaf(xv, wl, accl[r]);
            accr[r] = fmaf(xv, wr, accr[r]);
        }
    }
#pragma unroll
    for (int r = 0; r < RB; ++r) {
        hl[(size_t)(r0 + r) * DO + c] = accl[r];
        hr[(size_t)(r0 + r) * DO + c] = accr[r];
    }
}

// Batcher odd-even mergesort compare-exchange on (key, col) register pairs
#define CE(a,b) { \
    const bool pr_ = kk2[a] <= kk2[b]; \
    const unsigned klo_ = pr_ ? kk2[a] : kk2[b], khi_ = pr_ ? kk2[b] : kk2[a]; \
    const unsigned clo_ = pr_ ? cc2[a] : cc2[b], chi_ = pr_ ? cc2[b] : cc2[a]; \
    kk2[a] = klo_; kk2[b] = khi_; cc2[a] = clo_; cc2[b] = chi_; }

// f32 distances for a 16-row x 1024-col tile + per-row per-chunk top-32 set.
// d-loop: x rows broadcast from LDS, xT columns coalesced from global.
// selection: per-lane Batcher-16 sort -> transposed LDS heads -> 32 pops.
__global__ __launch_bounds__(256) void knn_partial_k(
    const float* __restrict__ x, const float* __restrict__ xT,
    const float* __restrict__ sq32, unsigned long long* __restrict__ keys)
{
    __shared__ float xs[RB * DI];               // 8 KB
    __shared__ unsigned dist4[4][CHUNK];        // 16 KB (fkey u32)
    __shared__ unsigned short col4[4][CHUNK];   // 8 KB

    const int r0 = blockIdx.x * RB;
    const int cbase = blockIdx.y * CHUNK;
    const int t = threadIdx.x;
    const int wid = t >> 6, lane = t & 63;

    {   // stage the 16 x-rows (contiguous 8 KB), float4-coalesced
        const float4* src = (const float4*)(x + (size_t)r0 * DI);
        float4* dst = (float4*)xs;
#pragma unroll
        for (int q = 0; q < (RB * DI / 4) / 256; ++q)
            dst[t + 256 * q] = src[t + 256 * q];
    }
    __syncthreads();

    float acc[RB][4];
#pragma unroll
    for (int r = 0; r < RB; ++r)
#pragma unroll
        for (int s = 0; s < 4; ++s) acc[r][s] = 0.f;

    const float* xTb = xT + cbase + t;
#pragma unroll 2
    for (int d = 0; d < DI; ++d) {
        float xv[4];
#pragma unroll
        for (int s = 0; s < 4; ++s) xv[s] = xTb[(size_t)d * NP2 + 256 * s];
#pragma unroll
        for (int r = 0; r < RB; ++r) {
            const float xr = xs[r * DI + d];            // LDS broadcast
#pragma unroll
            for (int s = 0; s < 4; ++s) acc[r][s] = fmaf(xr, xv[s], acc[r][s]);
        }
    }

    float sqi[RB], sqj[4];
#pragma unroll
    for (int r = 0; r < RB; ++r) sqi[r] = sq32[r0 + r];
#pragma unroll
    for (int s = 0; s < 4; ++s) sqj[s] = sq32[cbase + t + 256 * s];

#pragma unroll
    for (int p = 0; p < 4; ++p) {
        // write fkeys for rows 4p..4p+3 (conflict-free: bank = lane%32)
#pragma unroll
        for (int r4 = 0; r4 < 4; ++r4) {
            const int r = 4 * p + r4;
#pragma unroll
            for (int s = 0; s < 4; ++s) {
                const int pos = t + 256 * s;
                const int j = cbase + pos;
                const float dd = sqi[r] + sqj[s] - 2.f * acc[r][s];
                unsigned k = fkey(dd);
                if (j >= NN || j == r0 + r) k = 0xFFFFFFFEu;  // pad + diagonal
                dist4[r4][pos] = k;
            }
        }
        __syncthreads();

        // wave `wid` owns row 4p+wid: load 16 vals/lane
        unsigned kk2[16], cc2[16];
#pragma unroll
        for (int u = 0; u < 16; ++u) {
            const int pos = lane + 64 * u;
            kk2[u] = dist4[wid][pos];
            cc2[u] = (unsigned)pos;
        }
        // Batcher odd-even mergesort, n=16, 63 comparators
        CE(0,8) CE(1,9) CE(2,10) CE(3,11) CE(4,12) CE(5,13) CE(6,14) CE(7,15)
        CE(0,4) CE(1,5) CE(2,6) CE(3,7) CE(8,12) CE(9,13) CE(10,14) CE(11,15)
        CE(4,8) CE(5,9) CE(6,10) CE(7,11)
        CE(0,2) CE(1,3) CE(4,6) CE(5,7) CE(8,10) CE(9,11) CE(12,14) CE(13,15)
        CE(2,8) CE(3,9) CE(6,12) CE(7,13)
        CE(2,4) CE(3,5) CE(6,8) CE(7,9) CE(10,12) CE(11,13)
        CE(0,1) CE(2,3) CE(4,5) CE(6,7) CE(8,9) CE(10,11) CE(12,13) CE(14,15)
        CE(1,8) CE(3,10) CE(5,12) CE(7,14)
        CE(1,4) CE(3,6) CE(5,8) CE(7,10) CE(9,12) CE(11,14)
        CE(1,2) CE(3,4) CE(5,6) CE(7,8) CE(9,10) CE(11,12) CE(13,14)
        // write sorted heads transposed: addr u*64+lane -> bank lane%32 (free)
#pragma unroll
        for (int u = 0; u < 16; ++u) {
            dist4[wid][u * 64 + lane] = kk2[u];
            col4[wid][u * 64 + lane] = (unsigned short)cc2[u];
        }

        int hp = 0;
        unsigned headv = kk2[0];
        unsigned long long* outp =
            keys + ((size_t)(r0 + 4 * p + wid) * NCHUNK + blockIdx.y) * KNB;
#pragma unroll 1
        for (int k2 = 0; k2 < KNB; ++k2) {
            unsigned m = headv;
#pragma unroll
            for (int off = 32; off >= 1; off >>= 1) {
                const unsigned o = __shfl_xor(m, off);
                m = o < m ? o : m;
            }
            const unsigned long long won = __ballot(headv == m);
            const int wl = (int)__ffsll((long long)won) - 1;
            if (lane == wl) {
                const unsigned c = col4[wid][hp * 64 + lane];
                outp[k2] = ((unsigned long long)m << 32) | (unsigned)(cbase + c);
                ++hp;
                const int hq = hp < 16 ? hp : 15;
                const unsigned nv = dist4[wid][hq * 64 + lane];
                headv = hp < 16 ? nv : 0xFFFFFFFFu;
            }
        }
        __syncthreads();
    }
}

// merge 10 chunk-lists of 32 -> top-64 f32 candidates per row (one wave per row)
__global__ void knn_merge_k(const unsigned long long* __restrict__ keys,
                            int* __restrict__ cand)
{
    const int i = blockIdx.x;
    const int lane = threadIdx.x;   // 64 threads
    unsigned long long key[(NCHUNK * KNB) / 64];   // 5
#pragma unroll
    for (int u = 0; u < (NCHUNK * KNB) / 64; ++u)
        key[u] = keys[(size_t)i * (NCHUNK * KNB) + lane + 64 * u];
    for (int k = 0; k < CAND; ++k) {
        unsigned long long m = key[0];
#pragma unroll
        for (int u = 1; u < (NCHUNK * KNB) / 64; ++u) m = key[u] < m ? key[u] : m;
#pragma unroll
        for (int off = 32; off >= 1; off >>= 1) {
            unsigned long long o = __shfl_xor(m, off);
            m = o < m ? o : m;
        }
#pragma unroll
        for (int u = 0; u < (NCHUNK * KNB) / 64; ++u)
            if (key[u] == m) key[u] = ~0ull;   // remove winner
        if (lane == 0) cand[(size_t)i * CAND + k] = (int)(m & 0xffffffffu);
    }
}

// exact f64 re-rank of the 64 candidates -> final top-32 (lane = candidate)
__global__ void rerank_k(const double* __restrict__ x64, const double* __restrict__ sq64,
                         const int* __restrict__ cand, int* __restrict__ nbr)
{
    const int i = blockIdx.x;
    const int lane = threadIdx.x;   // 64
    const int c = cand[(size_t)i * CAND + lane];
    double acc = 0.0;
    for (int d = 0; d < DI; ++d)
        acc = fma(x64[(size_t)i * DI + d], x64[(size_t)c * DI + d], acc);
    const float dd = (float)(sq64[i] + sq64[c] - 2.0 * acc);
    unsigned long long key = ((unsigned long long)fkey(dd) << 32) | (unsigned)c;
    for (int k = 0; k < KNB; ++k) {
        unsigned long long m = key;
#pragma unroll
        for (int off = 32; off >= 1; off >>= 1) {
            unsigned long long o = __shfl_xor(m, off);
            m = o < m ? o : m;
        }
        if (key == m) key = ~0ull;   // unique winner removed
        if (lane == 0) nbr[(size_t)i * KNB + k] = (int)(m & 0xffffffffu);
    }
}

// attention epilogue: block=row, thread=output dim (DO==256==blockDim)
__global__ __launch_bounds__(256) void gat_k(
    const float* __restrict__ hl, const float* __restrict__ hr,
    const int* __restrict__ nbr, const float* __restrict__ att,
    const float* __restrict__ bias, float* __restrict__ out)
{
    __shared__ int src[NSRC];
    __shared__ float eP[NSRC][4];
    __shared__ float eS[NSRC];
    const int i = blockIdx.x, t = threadIdx.x;
    if (t < KNB) src[t] = nbr[(size_t)i * KNB + t];
    if (t == KNB) src[KNB] = i;   // self-loop appended last, like the reference
    __syncthreads();
    const float at  = att[t];
    const float hrv = hr[(size_t)i * DO + t];
    float hlv[NSRC];
#pragma unroll
    for (int k = 0; k < NSRC; ++k) {
        const float v = hl[(size_t)src[k] * DO + t];
        hlv[k] = v;
        const float z = v + hrv;
        float p = (z > 0.f ? z : NEG * z) * at;
#pragma unroll
        for (int off = 32; off >= 1; off >>= 1) p += __shfl_xor(p, off);
        if ((t & 63) == 0) eP[k][t >> 6] = p;
    }
    __syncthreads();
    if (t < NSRC) eS[t] = eP[t][0] + eP[t][1] + eP[t][2] + eP[t][3];
    __syncthreads();
    float m = eS[0];
#pragma unroll
    for (int k = 1; k < NSRC; ++k) m = fmaxf(m, eS[k]);
    float w[NSRC];
    float ssum = 0.f;
#pragma unroll
    for (int k = 0; k < NSRC; ++k) { w[k] = expf(eS[k] - m); ssum += w[k]; }
    const float inv = 1.f / ssum;
    float o = bias[t];
#pragma unroll
    for (int k = 0; k < NSRC; ++k) o = fmaf(w[k] * inv, hlv[k], o);
    out[(size_t)i * DO + t] = o;
}

extern "C" void kernel_launch(void* const* d_in, const int* in_sizes, int n_in,
                              void* d_out, int out_size, void* d_ws, size_t ws_size,
                              hipStream_t stream) {
    const float* x    = (const float*)d_in[0];
    const float* Wl   = (const float*)d_in[1];
    const float* bl   = (const float*)d_in[2];
    const float* Wr   = (const float*)d_in[3];
    const float* br   = (const float*)d_in[4];
    const float* att  = (const float*)d_in[5];
    const float* bias = (const float*)d_in[6];
    float* out = (float*)d_out;

    char* ws = (char*)d_ws;
    // layout (bytes):
    double* x64  = (double*)(ws + 0);           // 10,240,000
    float*  xT   = (float*)(ws + 10240000);     //  5,242,880
    double* sq64 = (double*)(ws + 15482880);    //     80,000
    float*  sq32 = (float*)(ws + 15562880);     //     40,960
    float*  hl   = (float*)(ws + 15603840);     // 10,240,000
    float*  hr   = (float*)(ws + 25843840);     // 10,240,000
    unsigned long long* keys = (unsigned long long*)(ws + 36083840); // 25,600,000
    int*    cand = (int*)(ws + 61683840);       //  2,560,000
    int*    nbr  = (int*)(ws + 64243840);       //  1,280,000
    // total ~65.5 MB

    cast_k<<<dim3((NN * DI + 255) / 256), 256, 0, stream>>>(x, x64);
    transpose32_k<<<dim3(NP2 / 256, DI), 256, 0, stream>>>(x, xT);
    sqrow_k<<<dim3(NP2 / 256), 256, 0, stream>>>(x64, sq64, sq32);
    hgemm_k<<<dim3(NN / RB), 256, 0, stream>>>(x, Wl, bl, Wr, br, hl, hr);
    knn_partial_k<<<dim3(NN / RB, NCHUNK), 256, 0, stream>>>(x, xT, sq32, keys);
    knn_merge_k<<<dim3(NN), 64, 0, stream>>>(keys, cand);
    rerank_k<<<dim3(NN), 64, 0, stream>>>(x64, sq64, cand, nbr);
    gat_k<<<dim3(NN), 256, 0, stream>>>(hl, hr, nbr, att, bias, out);
}